// Round 1
// baseline (864.316 us; speedup 1.0000x reference)
//
#include <hip/hip_runtime.h>
#include <math.h>

#define C_IN 4
#define C_OUTC 8
#define N_ROT 8
#define R_B 8
#define KS 5
#define HW 256

#define PI_F      3.14159265358979323846f
#define TWO_PI_F  6.28318530717958647692f
#define PI4_F     0.78539816339744830962f   // pi/4 == ROT_SCALE == 2pi/8

__device__ __forceinline__ float sgn(float t) {
    return (t > 0.f) ? 1.f : ((t < 0.f) ? -1.f : 0.f);
}

// quadratic B-spline, exactly per reference
__device__ __forceinline__ float b2(float x) {
    float a = x - 0.5f;
    float b = x - 1.5f;
    float c = 1.f + 2.f * x;
    float d = 3.f + 2.f * x;
    return (-3.f * a * a * sgn(0.5f - x)
            + b * b * sgn(1.5f - x)
            - 0.75f * c * c * sgn(0.5f + x)
            + 0.25f * d * d * sgn(1.5f + x)) * 0.25f;
}

// ks_l[I][t][O], O = r0*8+o contiguous (64 floats). I = i*8+r (0..31), t = dx*5+dy (0..24).
// ks_l[(I*25+t)*64 + O] = sum_m xx_vals_{r0}[dx,dy,m] * rot_vals_{r0}[r,m] * weights[i,m,o]
__global__ void build_ks_kernel(const float* __restrict__ w, float* __restrict__ ksl) {
    int g = blockIdx.x * 256 + threadIdx.x;
    if (g >= 64 * 32 * 25) return;
    int O = g & 63;
    int rest = g >> 6;            // 0..799
    int t = rest % 25;
    int I = rest / 25;            // 0..31
    int r0 = O >> 3, o = O & 7;
    int i = I >> 3, r = I & 7;
    int x = t / 5, y = t % 5;

    float theta = -(float)r0 * PI4_F;
    float cth = cosf(theta), sth = sinf(theta);
    float fx = (float)(x - 2), fy = (float)(y - 2);
    float xc = fx * cth - fy * sth;    // rotated sample coords
    float yc = fx * sth + fy * cth;

    // rot_vals[r, m%8] for this (r, r0): B2(angle_dist(rot_sample[r]+theta, mr*pi/4)/ROT_SCALE)
    float rotv[8];
    float rs = (float)r * PI4_F + theta;
    #pragma unroll
    for (int mr = 0; mr < 8; ++mr) {
        float v = (float)mr * PI4_F - rs + PI_F;
        float md = fmodf(v, TWO_PI_F);
        if (md < 0.f) md += TWO_PI_F;
        rotv[mr] = b2((md - PI_F) / PI4_F);
    }

    float sum = 0.f;
    for (int mx = 0; mx < 25; ++mx) {
        float cx = (float)(mx / 5 - 2);
        float cy = (float)(mx % 5 - 2);
        float bx = b2(cx - xc) * b2(cy - yc);
        if (bx != 0.f) {
            const float* wp = w + (size_t)(i * 200 + mx * 8) * 8 + o;
            #pragma unroll
            for (int mr = 0; mr < 8; ++mr)
                sum = fmaf(bx * rotv[mr], wp[mr * 8], sum);
        }
    }
    ksl[(size_t)(I * 25 + t) * 64 + O] = sum;
}

// Direct conv. Block: 512 threads = 8 waves. Tile: 16x16 pixels, all 64 O channels.
// wave = r0 (0..7); within wave: row = lane>>2 (0..15), col0 = (lane&3)*4.
// Each thread: 4 consecutive px (cols col0..col0+3) x 8 oc (o = 0..7) accumulators.
__global__ __launch_bounds__(512, 4) void conv_kernel(const float* __restrict__ X,
                                                      const float* __restrict__ ksl,
                                                      float* __restrict__ out) {
    __shared__ float tile[32 * 20 * 24];   // [I][rr 0..19][cc 0..23], 61.44 KB

    int blk = blockIdx.x;
    int b = blk >> 8;            // 8 batches
    int tt = blk & 255;          // 16x16 tiles
    int h0 = (tt >> 4) << 4;
    int w0 = (tt & 15) << 4;
    int tid = threadIdx.x;

    // ---- stage input tile (with halo 2, zero-padded) ----
    const float* Xb = X + (size_t)b * 32 * HW * HW;
    for (int lin = tid; lin < 32 * 20 * 24; lin += 512) {
        int I = lin / 480;
        int rem = lin - I * 480;
        int rr = rem / 24;
        int cc = rem - rr * 24;
        float v = 0.f;
        int gh = h0 + rr - 2;
        int gw = w0 + cc - 2;
        if (cc < 20 && (unsigned)gh < (unsigned)HW && (unsigned)gw < (unsigned)HW)
            v = Xb[(size_t)I * HW * HW + gh * HW + gw];
        tile[lin] = v;
    }
    __syncthreads();

    int wave = tid >> 6;          // = r0
    int lane = tid & 63;
    int row  = lane >> 2;         // 0..15
    int col0 = (lane & 3) << 2;   // 0,4,8,12
    int oc0  = wave << 3;         // O base for this wave

    float4 acc[8];
    #pragma unroll
    for (int c = 0; c < 8; ++c) acc[c] = make_float4(0.f, 0.f, 0.f, 0.f);

    for (int I = 0; I < 32; ++I) {
        const float* tI = &tile[I * 480];
        #pragma unroll
        for (int dx = 0; dx < 5; ++dx) {
            const float* trow = &tI[(row + dx) * 24 + col0];
            float4 xa = *(const float4*)(trow);
            float4 xb = *(const float4*)(trow + 4);
            float xr[8] = {xa.x, xa.y, xa.z, xa.w, xb.x, xb.y, xb.z, xb.w};
            #pragma unroll
            for (int dy = 0; dy < 5; ++dy) {
                const float4* kp = (const float4*)&ksl[(size_t)(I * 25 + dx * 5 + dy) * 64 + oc0];
                float4 k0 = kp[0];
                float4 k1 = kp[1];
                float kv[8] = {k0.x, k0.y, k0.z, k0.w, k1.x, k1.y, k1.z, k1.w};
                #pragma unroll
                for (int c = 0; c < 8; ++c) {
                    float kk = kv[c];
                    acc[c].x = fmaf(xr[dy + 0], kk, acc[c].x);
                    acc[c].y = fmaf(xr[dy + 1], kk, acc[c].y);
                    acc[c].z = fmaf(xr[dy + 2], kk, acc[c].z);
                    acc[c].w = fmaf(xr[dy + 3], kk, acc[c].w);
                }
            }
        }
    }

    // ---- store: out[b][o=c][r0=wave][h][w] * (2pi/8) ----
    const float SCALE = PI4_F;
    #pragma unroll
    for (int c = 0; c < 8; ++c) {
        float4 v = acc[c];
        v.x *= SCALE; v.y *= SCALE; v.z *= SCALE; v.w *= SCALE;
        float* op = out + ((size_t)((b * 8 + c) * 8 + wave)) * HW * HW
                        + (size_t)(h0 + row) * HW + (w0 + col0);
        *(float4*)op = v;
    }
}

extern "C" void kernel_launch(void* const* d_in, const int* in_sizes, int n_in,
                              void* d_out, int out_size, void* d_ws, size_t ws_size,
                              hipStream_t stream) {
    const float* X = (const float*)d_in[0];       // (8, 4, 8, 256, 256) f32
    const float* w = (const float*)d_in[1];       // (4, 200, 8) f32
    float* outp = (float*)d_out;                  // (8, 8, 8, 256, 256) f32
    float* ksl = (float*)d_ws;                    // 32*25*64 floats = 204.8 KB

    // kernel stack build: 51200 elements
    build_ks_kernel<<<(64 * 32 * 25 + 255) / 256, 256, 0, stream>>>(w, ksl);

    // conv: 8 batches x 16x16 tiles of 16x16 px
    conv_kernel<<<8 * 16 * 16, 512, 0, stream>>>(X, ksl, outp);
}

// Round 2
// 114.085 us; speedup vs baseline: 7.5761x; 7.5761x over previous
//
#include <hip/hip_runtime.h>
#include <hip/hip_fp16.h>
#include <math.h>

#define PI_F      3.14159265358979323846f
#define TWO_PI_F  6.28318530717958647692f
#define PI4_F     0.78539816339744830962f   // pi/4 == ROT_SCALE == 2pi/8

typedef _Float16 f16x8 __attribute__((ext_vector_type(8)));
typedef float    f32x4 __attribute__((ext_vector_type(4)));

__device__ __forceinline__ float sgn(float t) {
    return (t > 0.f) ? 1.f : ((t < 0.f) ? -1.f : 0.f);
}

// quadratic B-spline, exactly per reference
__device__ __forceinline__ float b2(float x) {
    float a = x - 0.5f;
    float b = x - 1.5f;
    float c = 1.f + 2.f * x;
    float d = 3.f + 2.f * x;
    return (-3.f * a * a * sgn(0.5f - x)
            + b * b * sgn(1.5f - x)
            - 0.75f * c * c * sgn(0.5f + x)
            + 0.25f * d * d * sgn(1.5f + x)) * 0.25f;
}

// ks_h[t][O][I] fp16.  t = dx*5+dy (0..24), O = r0*8+o (0..63), I = i*8+r (0..31)
__global__ void build_ks_kernel(const float* __restrict__ w, __half* __restrict__ ksh) {
    int g = blockIdx.x * 256 + threadIdx.x;
    if (g >= 64 * 32 * 25) return;
    int O = g & 63;
    int rest = g >> 6;            // 0..799
    int t = rest % 25;
    int I = rest / 25;            // 0..31
    int r0 = O >> 3, o = O & 7;
    int i = I >> 3, r = I & 7;
    int x = t / 5, y = t % 5;

    float theta = -(float)r0 * PI4_F;
    float cth = cosf(theta), sth = sinf(theta);
    float fx = (float)(x - 2), fy = (float)(y - 2);
    float xc = fx * cth - fy * sth;
    float yc = fx * sth + fy * cth;

    float rotv[8];
    float rs = (float)r * PI4_F + theta;
    #pragma unroll
    for (int mr = 0; mr < 8; ++mr) {
        float v = (float)mr * PI4_F - rs + PI_F;
        float md = fmodf(v, TWO_PI_F);
        if (md < 0.f) md += TWO_PI_F;
        rotv[mr] = b2((md - PI_F) / PI4_F);
    }

    float sum = 0.f;
    for (int mx = 0; mx < 25; ++mx) {
        float cx = (float)(mx / 5 - 2);
        float cy = (float)(mx % 5 - 2);
        float bx = b2(cx - xc) * b2(cy - yc);
        if (bx != 0.f) {
            const float* wp = w + (size_t)(i * 200 + mx * 8) * 8 + o;
            #pragma unroll
            for (int mr = 0; mr < 8; ++mr)
                sum = fmaf(bx * rotv[mr], wp[mr * 8], sum);
        }
    }
    ksh[(size_t)(t * 64 + O) * 32 + I] = __float2half(sum);
}

// Implicit-GEMM conv via 25 shifted MFMA GEMMs.
// Block: 512 threads = 8 waves; output tile 16h x 32w px, all 64 O.
// LDS: X tile transposed to [px(r*36+c)][I] fp16, rows of 64B, stored as uint4 slots.
// Wave w owns output rows {2w, 2w+1} = 4 M-tiles (16 px each) x 4 N-tiles (64 O).
__global__ __launch_bounds__(512, 4) void conv_kernel(const float* __restrict__ X,
                                                      const __half* __restrict__ ksh,
                                                      float* __restrict__ out) {
    __shared__ uint4 xt[20 * 36 * 4];   // [px][slot] ; slot = 8 consecutive I ; 46.08 KB

    int blk = blockIdx.x;
    int b = blk >> 7;                 // 8 batches
    int rem = blk & 127;
    int h0 = (rem >> 3) << 4;         // 16 h-tiles of 16
    int w0 = (rem & 7) << 5;          // 8 w-tiles of 32
    int tid = threadIdx.x;

    const float* Xb = X + (size_t)b * 32 * 65536;

    // ---- stage: global [I][h][w] f32 -> LDS [px][I] fp16 (transpose + convert) ----
    for (int lin = tid; lin < 2880; lin += 512) {
        int slot = lin / 720;             // 0..3 -> I = slot*8 + j
        int pxi = lin - slot * 720;       // 0..719
        int r = pxi / 36;
        int c = pxi - r * 36;
        int gh = h0 + r - 2;
        int gw = w0 + c - 2;
        union { __half h[8]; uint4 u; } pk;
        if ((unsigned)gh < 256u && (unsigned)gw < 256u) {
            const float* src = Xb + (size_t)slot * 8 * 65536 + gh * 256 + gw;
            #pragma unroll
            for (int j = 0; j < 8; ++j) pk.h[j] = __float2half(src[j * 65536]);
        } else {
            pk.u = make_uint4(0u, 0u, 0u, 0u);
        }
        xt[pxi * 4 + slot] = pk.u;
    }
    __syncthreads();

    int wave = tid >> 6;
    int lane = tid & 63;
    int lO = lane & 15;       // A-row px / B-col O / D-col O
    int ks4 = lane >> 4;      // k-slot for A/B ; D-row group

    const uint4* ksq = (const uint4*)ksh;
    int bidx = lO * 4 + ks4;

    f32x4 acc[4][4] = {};

    int baseA[4];
    #pragma unroll
    for (int q = 0; q < 4; ++q) {
        int r_q = wave * 2 + (q >> 1);
        int half_q = q & 1;
        baseA[q] = (r_q * 36 + half_q * 16 + lO) * 4 + ks4;
    }

    for (int dx = 0; dx < 5; ++dx) {
        #pragma unroll
        for (int dy = 0; dy < 5; ++dy) {
            int t = dx * 5 + dy;
            f16x8 Bf[4], Af[4];
            #pragma unroll
            for (int n = 0; n < 4; ++n)
                Bf[n] = __builtin_bit_cast(f16x8, ksq[t * 256 + n * 64 + bidx]);
            #pragma unroll
            for (int q = 0; q < 4; ++q)
                Af[q] = __builtin_bit_cast(f16x8, xt[baseA[q] + (dx * 36 + dy) * 4]);
            #pragma unroll
            for (int q = 0; q < 4; ++q) {
                #pragma unroll
                for (int n = 0; n < 4; ++n)
                    acc[q][n] = __builtin_amdgcn_mfma_f32_16x16x32_f16(Af[q], Bf[n], acc[q][n], 0, 0, 0);
            }
        }
    }

    // ---- store: out[b][O&7][O>>3][h][w] * (2pi/8) ----
    #pragma unroll
    for (int q = 0; q < 4; ++q) {
        int r_q = wave * 2 + (q >> 1);
        int gh = h0 + r_q;
        int gwb = w0 + (q & 1) * 16 + ks4 * 4;   // D row = ks4*4 + reg
        #pragma unroll
        for (int n = 0; n < 4; ++n) {
            int O = n * 16 + lO;
            float* op = out + (((size_t)(b * 8 + (O & 7)) * 8 + (O >> 3)) << 16)
                            + gh * 256 + gwb;
            f32x4 v = acc[q][n] * PI4_F;
            *(f32x4*)op = v;
        }
    }
}

extern "C" void kernel_launch(void* const* d_in, const int* in_sizes, int n_in,
                              void* d_out, int out_size, void* d_ws, size_t ws_size,
                              hipStream_t stream) {
    const float* X = (const float*)d_in[0];       // (8, 4, 8, 256, 256) f32
    const float* w = (const float*)d_in[1];       // (4, 200, 8) f32
    float* outp = (float*)d_out;                  // (8, 8, 8, 256, 256) f32
    __half* ksh = (__half*)d_ws;                  // 25*64*32 fp16 = 102.4 KB

    build_ks_kernel<<<(64 * 32 * 25 + 255) / 256, 256, 0, stream>>>(w, ksh);
    conv_kernel<<<8 * 16 * 8, 512, 0, stream>>>(X, ksh, outp);
}

// Round 3
// 110.585 us; speedup vs baseline: 7.8159x; 1.0317x over previous
//
#include <hip/hip_runtime.h>
#include <hip/hip_fp16.h>
#include <math.h>

#define PI_F      3.14159265358979323846f
#define TWO_PI_F  6.28318530717958647692f
#define PI4_F     0.78539816339744830962f   // pi/4 == ROT_SCALE == 2pi/8

typedef _Float16 f16x8 __attribute__((ext_vector_type(8)));
typedef float    f32x4 __attribute__((ext_vector_type(4)));

__device__ __forceinline__ float sgn(float t) {
    return (t > 0.f) ? 1.f : ((t < 0.f) ? -1.f : 0.f);
}

// quadratic B-spline, exactly per reference
__device__ __forceinline__ float b2(float x) {
    float a = x - 0.5f;
    float b = x - 1.5f;
    float c = 1.f + 2.f * x;
    float d = 3.f + 2.f * x;
    return (-3.f * a * a * sgn(0.5f - x)
            + b * b * sgn(1.5f - x)
            - 0.75f * c * c * sgn(0.5f + x)
            + 0.25f * d * d * sgn(1.5f + x)) * 0.25f;
}

// ks_h[t][O][I] fp16.  t = dx*5+dy (0..24), O = r0*8+o (0..63), I = i*8+r (0..31)
__global__ void build_ks_kernel(const float* __restrict__ w, __half* __restrict__ ksh) {
    int g = blockIdx.x * 256 + threadIdx.x;
    if (g >= 64 * 32 * 25) return;
    int O = g & 63;
    int rest = g >> 6;            // 0..799
    int t = rest % 25;
    int I = rest / 25;            // 0..31
    int r0 = O >> 3, o = O & 7;
    int i = I >> 3, r = I & 7;
    int x = t / 5, y = t % 5;

    float theta = -(float)r0 * PI4_F;
    float cth = cosf(theta), sth = sinf(theta);
    float fx = (float)(x - 2), fy = (float)(y - 2);
    float xc = fx * cth - fy * sth;
    float yc = fx * sth + fy * cth;

    float rotv[8];
    float rs = (float)r * PI4_F + theta;
    #pragma unroll
    for (int mr = 0; mr < 8; ++mr) {
        float v = (float)mr * PI4_F - rs + PI_F;
        float md = fmodf(v, TWO_PI_F);
        if (md < 0.f) md += TWO_PI_F;
        rotv[mr] = b2((md - PI_F) / PI4_F);
    }

    float sum = 0.f;
    for (int mx = 0; mx < 25; ++mx) {
        float cx = (float)(mx / 5 - 2);
        float cy = (float)(mx % 5 - 2);
        float bx = b2(cx - xc) * b2(cy - yc);
        if (bx != 0.f) {
            const float* wp = w + (size_t)(i * 200 + mx * 8) * 8 + o;
            #pragma unroll
            for (int mr = 0; mr < 8; ++mr)
                sum = fmaf(bx * rotv[mr], wp[mr * 8], sum);
        }
    }
    ksh[(size_t)(t * 64 + O) * 32 + I] = __float2half(sum);
}

// Implicit-GEMM conv via 25 shifted MFMA GEMMs.
// Block: 512 threads = 8 waves; output tile 16h x 32w px, all 64 O.
// LDS: X tile transposed to [px(r*36+c)][I] fp16, padded to 5 uint4 slots per px
// (80 B row stride -> 2-way banks instead of 8-way at 64 B).
// Wave w owns output rows {2w, 2w+1} = 4 M-tiles (16 px each) x 4 N-tiles (64 O).
__global__ __launch_bounds__(512, 4) void conv_kernel(const float* __restrict__ X,
                                                      const __half* __restrict__ ksh,
                                                      float* __restrict__ out) {
    __shared__ uint4 xt[720 * 5];   // [px][slot(5, 4 used)] ; 57.6 KB

    int blk = blockIdx.x;
    int b = blk >> 7;                 // 8 batches
    int rem = blk & 127;
    int h0 = (rem >> 3) << 4;         // 16 h-tiles of 16
    int w0 = (rem & 7) << 5;          // 8 w-tiles of 32
    int tid = threadIdx.x;

    const float* Xb = X + (size_t)b * 32 * 65536;

    // ---- stage: global [I][h][w] f32 -> LDS [px][I] fp16 (transpose + convert) ----
    for (int lin = tid; lin < 2880; lin += 512) {
        int slot = lin / 720;             // 0..3 -> I = slot*8 + j
        int pxi = lin - slot * 720;       // 0..719
        int r = pxi / 36;
        int c = pxi - r * 36;
        int gh = h0 + r - 2;
        int gw = w0 + c - 2;
        union { __half h[8]; uint4 u; } pk;
        if ((unsigned)gh < 256u && (unsigned)gw < 256u) {
            const float* src = Xb + (size_t)slot * 8 * 65536 + gh * 256 + gw;
            #pragma unroll
            for (int j = 0; j < 8; ++j) pk.h[j] = __float2half(src[j * 65536]);
        } else {
            pk.u = make_uint4(0u, 0u, 0u, 0u);
        }
        xt[pxi * 5 + slot] = pk.u;
    }
    __syncthreads();

    int wave = tid >> 6;
    int lane = tid & 63;
    int lO = lane & 15;       // A-row px / B-col O / D-col O
    int ks4 = lane >> 4;      // k-slot for A/B ; D-row group

    const uint4* ksq = (const uint4*)ksh;
    int bidx = lO * 4 + ks4;

    f32x4 acc[4][4] = {};

    int baseA[4];
    #pragma unroll
    for (int q = 0; q < 4; ++q) {
        int r_q = wave * 2 + (q >> 1);
        int half_q = q & 1;
        baseA[q] = (r_q * 36 + half_q * 16 + lO) * 5 + ks4;
    }

    // ---- 25-tap fully-unrolled MFMA loop with 1-deep B double buffer ----
    f16x8 Bf[2][4];
    #pragma unroll
    for (int n = 0; n < 4; ++n)
        Bf[0][n] = __builtin_bit_cast(f16x8, ksq[0 * 256 + n * 64 + bidx]);

    #pragma unroll
    for (int t = 0; t < 25; ++t) {
        const int dx = t / 5, dy = t % 5;
        const int aoff = (dx * 36 + dy) * 5;
        const int cur = t & 1, nxt = cur ^ 1;

        f16x8 Af[4];
        #pragma unroll
        for (int q = 0; q < 4; ++q)
            Af[q] = __builtin_bit_cast(f16x8, xt[baseA[q] + aoff]);

        if (t < 24) {
            #pragma unroll
            for (int n = 0; n < 4; ++n)
                Bf[nxt][n] = __builtin_bit_cast(f16x8, ksq[(t + 1) * 256 + n * 64 + bidx]);
        }

        #pragma unroll
        for (int q = 0; q < 4; ++q) {
            #pragma unroll
            for (int n = 0; n < 4; ++n)
                acc[q][n] = __builtin_amdgcn_mfma_f32_16x16x32_f16(Af[q], Bf[cur][n], acc[q][n], 0, 0, 0);
        }
    }

    // ---- store: out[b][O&7][O>>3][h][w] * (2pi/8) ----
    #pragma unroll
    for (int q = 0; q < 4; ++q) {
        int r_q = wave * 2 + (q >> 1);
        int gh = h0 + r_q;
        int gwb = w0 + (q & 1) * 16 + ks4 * 4;   // D row = ks4*4 + reg
        #pragma unroll
        for (int n = 0; n < 4; ++n) {
            int O = n * 16 + lO;
            float* op = out + (((size_t)(b * 8 + (O & 7)) * 8 + (O >> 3)) << 16)
                            + gh * 256 + gwb;
            f32x4 v = acc[q][n] * PI4_F;
            *(f32x4*)op = v;
        }
    }
}

extern "C" void kernel_launch(void* const* d_in, const int* in_sizes, int n_in,
                              void* d_out, int out_size, void* d_ws, size_t ws_size,
                              hipStream_t stream) {
    const float* X = (const float*)d_in[0];       // (8, 4, 8, 256, 256) f32
    const float* w = (const float*)d_in[1];       // (4, 200, 8) f32
    float* outp = (float*)d_out;                  // (8, 8, 8, 256, 256) f32
    __half* ksh = (__half*)d_ws;                  // 25*64*32 fp16 = 102.4 KB

    build_ks_kernel<<<(64 * 32 * 25 + 255) / 256, 256, 0, stream>>>(w, ksh);
    conv_kernel<<<8 * 16 * 8, 512, 0, stream>>>(X, ksh, outp);
}